// Round 4
// baseline (747.108 us; speedup 1.0000x reference)
//
#include <hip/hip_runtime.h>

#define Bsz 4096
#define Fsz 32
#define Dsz 64
#define Psz 496
#define RPW 64      // b-rows per wave
#define WPB 4       // waves per block (256 threads)

// One wave owns one pair p and RPW consecutive b-rows.
// Lane e (0..63) holds the full column W[p][:, e] in 64 VGPRs, PINNED via
// empty inline-asm so the register allocator cannot rematerialize the
// (invariant) global loads inside the row loop. Round-3 counters proved
// that remat happened: VGPR_Count=36, FETCH_SIZE 197 MB (5x overfetch),
// VALU issue 2.2x the useful FMA work.
// Per row: vi[b] is wave-uniform -> scalar loads (SGPRs, s_load_dwordx16);
// 64 v_fmac with SGPR src0; single sequential fmaf chain keeps bitwise
// accumulation order identical (absmax==0.0 preserved).
__global__ __launch_bounds__(256, 4)   // min 4 waves/EU -> VGPR cap 128
void bilinear_wreg_kernel(const float* __restrict__ in,
                          const float* __restrict__ W,
                          float* __restrict__ out)
{
    const int p    = blockIdx.x;
    const int tid  = threadIdx.x;
    const int lane = tid & 63;

    // Wave-uniform base row in an SGPR so vi loads scalarize.
    const int bb0 = __builtin_amdgcn_readfirstlane(
                        blockIdx.y * (RPW * WPB) + (tid >> 6) * RPW);

    // Decode pair p -> (i, j), matching np.triu_indices(F, k=1) order.
    int i = 0, rem = p;
    while (rem >= Fsz - 1 - i) { rem -= Fsz - 1 - i; ++i; }
    const int j = i + 1 + rem;

    // Load W[p] column 'lane' into registers (64 coalesced dword loads,
    // 256 B/instruction across the wave), then PIN each value in a VGPR.
    float w[Dsz];
    {
        const float* Wp = W + (size_t)p * (Dsz * Dsz) + lane;
#pragma unroll
        for (int d = 0; d < Dsz; ++d) w[d] = Wp[(size_t)d * Dsz];
    }
#pragma unroll
    for (int d = 0; d < Dsz; ++d) {
        // Opaque touch: value becomes an asm output -> not rematerializable,
        // forcing w[] to stay resident in 64 VGPRs across the row loop.
        asm volatile("" : "+v"(w[d]));
    }

    const float* __restrict__ vi0 = in  + ((size_t)bb0 * Fsz + i) * Dsz;         // uniform
    const float* __restrict__ vj0 = in  + ((size_t)bb0 * Fsz + j) * Dsz + lane;  // per-lane
    float*       __restrict__ op0 = out + ((size_t)bb0 * Psz + p) * Dsz + lane;  // per-lane

#pragma unroll 1
    for (int r = 0; r < RPW; ++r) {
        const float* vi  = vi0 + (size_t)r * (Fsz * Dsz);   // wave-uniform address
        const float  vjv = vj0[(size_t)r * (Fsz * Dsz)];    // 256 B coalesced load

        // Whole vi row into scalar registers (4x s_load_dwordx16).
        float s[Dsz];
#pragma unroll
        for (int d = 0; d < Dsz; ++d) s[d] = vi[d];

        // 64 back-to-back v_fmac_f32 acc, s[d], w[d] — zero LDS, no remat.
        float acc = 0.0f;
#pragma unroll
        for (int d = 0; d < Dsz; ++d) acc = fmaf(s[d], w[d], acc);

        // 256 B contiguous per wave-instruction; nontemporal keeps the
        // 520 MB output stream out of L2/L3 so 'in' + W stay resident.
        __builtin_nontemporal_store(acc * vjv, op0 + (size_t)r * (Psz * Dsz));
    }
}

extern "C" void kernel_launch(void* const* d_in, const int* in_sizes, int n_in,
                              void* d_out, int out_size, void* d_ws, size_t ws_size,
                              hipStream_t stream) {
    const float* in  = (const float*)d_in[0];
    const float* W   = (const float*)d_in[1];
    float*       out = (float*)d_out;

    dim3 grid(Psz, Bsz / (RPW * WPB));   // (496, 16)
    bilinear_wreg_kernel<<<grid, 256, 0, stream>>>(in, W, out);
}

// Round 5
// 746.022 us; speedup vs baseline: 1.0015x; 1.0015x over previous
//
#include <hip/hip_runtime.h>

#define Bsz 4096
#define Fsz 32
#define Dsz 64
#define Psz 496
#define RPW 64      // b-rows per wave
#define WPB 4       // waves per block (256 threads)

// Explicit-asm load of one W element per lane: dst <- ptr[OFF bytes].
// An asm def cannot be rematerialized by the register allocator, so the
// W column is FORCED to stay resident in 64 VGPRs across the row loop.
// (Rounds 3/4 proved the compiler otherwise re-issues these invariant
// loads every row: VGPR=36, FETCH 200 MB = 5x overfetch, ~2.2x VALU issue.)
#define LDW(dst, ptr, OFF) \
    asm volatile("global_load_dword %0, %1, off offset:" #OFF \
                 : "=v"(dst) : "v"(ptr))

__global__ __launch_bounds__(256, 4)   // cap VGPR at 128 (4 waves/EU)
void bilinear_wreg2_kernel(const float* __restrict__ in,
                           const float* __restrict__ W,
                           float* __restrict__ out)
{
    const int p    = blockIdx.x;
    const int tid  = threadIdx.x;
    const int lane = tid & 63;

    // Wave-uniform base row in an SGPR so vi loads scalarize (s_load_dwordx16).
    const int bb0 = __builtin_amdgcn_readfirstlane(
                        blockIdx.y * (RPW * WPB) + (tid >> 6) * RPW);

    // Decode pair p -> (i, j), matching np.triu_indices(F, k=1) order.
    int i = 0, rem = p;
    while (rem >= Fsz - 1 - i) { rem -= Fsz - 1 - i; ++i; }
    const int j = i + 1 + rem;

    // ---- W[p] column 'lane' -> 64 pinned VGPRs ----
    // w[d] holds W[p][d][lane]; each asm load is a 256 B coalesced
    // wave-instruction. 13-bit offset immediate => 4 base pointers.
    float w[Dsz];
    {
        const float* b0p = W + (size_t)p * (Dsz * Dsz) + lane;  // rows  0..15
        const float* b1p = b0p + 16 * Dsz;                      // rows 16..31
        const float* b2p = b0p + 32 * Dsz;                      // rows 32..47
        const float* b3p = b0p + 48 * Dsz;                      // rows 48..63
        LDW(w[ 0], b0p,    0); LDW(w[ 1], b0p,  256); LDW(w[ 2], b0p,  512); LDW(w[ 3], b0p,  768);
        LDW(w[ 4], b0p, 1024); LDW(w[ 5], b0p, 1280); LDW(w[ 6], b0p, 1536); LDW(w[ 7], b0p, 1792);
        LDW(w[ 8], b0p, 2048); LDW(w[ 9], b0p, 2304); LDW(w[10], b0p, 2560); LDW(w[11], b0p, 2816);
        LDW(w[12], b0p, 3072); LDW(w[13], b0p, 3328); LDW(w[14], b0p, 3584); LDW(w[15], b0p, 3840);
        LDW(w[16], b1p,    0); LDW(w[17], b1p,  256); LDW(w[18], b1p,  512); LDW(w[19], b1p,  768);
        LDW(w[20], b1p, 1024); LDW(w[21], b1p, 1280); LDW(w[22], b1p, 1536); LDW(w[23], b1p, 1792);
        LDW(w[24], b1p, 2048); LDW(w[25], b1p, 2304); LDW(w[26], b1p, 2560); LDW(w[27], b1p, 2816);
        LDW(w[28], b1p, 3072); LDW(w[29], b1p, 3328); LDW(w[30], b1p, 3584); LDW(w[31], b1p, 3840);
        LDW(w[32], b2p,    0); LDW(w[33], b2p,  256); LDW(w[34], b2p,  512); LDW(w[35], b2p,  768);
        LDW(w[36], b2p, 1024); LDW(w[37], b2p, 1280); LDW(w[38], b2p, 1536); LDW(w[39], b2p, 1792);
        LDW(w[40], b2p, 2048); LDW(w[41], b2p, 2304); LDW(w[42], b2p, 2560); LDW(w[43], b2p, 2816);
        LDW(w[44], b2p, 3072); LDW(w[45], b2p, 3328); LDW(w[46], b2p, 3584); LDW(w[47], b2p, 3840);
        LDW(w[48], b3p,    0); LDW(w[49], b3p,  256); LDW(w[50], b3p,  512); LDW(w[51], b3p,  768);
        LDW(w[52], b3p, 1024); LDW(w[53], b3p, 1280); LDW(w[54], b3p, 1536); LDW(w[55], b3p, 1792);
        LDW(w[56], b3p, 2048); LDW(w[57], b3p, 2304); LDW(w[58], b3p, 2560); LDW(w[59], b3p, 2816);
        LDW(w[60], b3p, 3072); LDW(w[61], b3p, 3328); LDW(w[62], b3p, 3584); LDW(w[63], b3p, 3840);
    }
    // Drain the asm loads; sched_barrier stops the compiler from hoisting
    // register-only FMAs above the wait (rule #18 — the waitcnt pass does
    // not model asm loads, and "memory" doesn't order register-only ops).
    asm volatile("s_waitcnt vmcnt(0)" ::: "memory");
    __builtin_amdgcn_sched_barrier(0);

    const float* vi = in  + ((size_t)bb0 * Fsz + i) * Dsz;          // uniform
    const float* vj = in  + ((size_t)bb0 * Fsz + j) * Dsz + lane;   // per-lane
    float*       op = out + ((size_t)bb0 * Psz + p) * Dsz + lane;   // per-lane

#pragma unroll 1
    for (int r = 0; r < RPW; ++r) {
        // Whole vi row into scalar registers (4x s_load_dwordx16).
        float s[Dsz];
#pragma unroll
        for (int d = 0; d < Dsz; ++d) s[d] = vi[d];

        const float vjv = *vj;   // 256 B coalesced vector load

        // 64 back-to-back v_fmac_f32 acc, s[d], w[d] — zero LDS, no remat.
        float acc = 0.0f;
#pragma unroll
        for (int d = 0; d < Dsz; ++d) acc = fmaf(s[d], w[d], acc);

        // 256 B contiguous per wave-instruction; nontemporal keeps the
        // 520 MB output stream out of L2/L3 so 'in' + W stay resident.
        __builtin_nontemporal_store(acc * vjv, op);

        vi += Fsz * Dsz;
        vj += Fsz * Dsz;
        op += (size_t)Psz * Dsz;
    }
}

extern "C" void kernel_launch(void* const* d_in, const int* in_sizes, int n_in,
                              void* d_out, int out_size, void* d_ws, size_t ws_size,
                              hipStream_t stream) {
    const float* in  = (const float*)d_in[0];
    const float* W   = (const float*)d_in[1];
    float*       out = (float*)d_out;

    dim3 grid(Psz, Bsz / (RPW * WPB));   // (496, 16)
    bilinear_wreg2_kernel<<<grid, 256, 0, stream>>>(in, W, out);
}